// Round 11
// baseline (13880.223 us; speedup 1.0000x reference)
//
#include <hip/hip_runtime.h>

// ---------------------------------------------------------------------------
// Decoder_49005576847865 — persistent decoder, independent batch groups.
//   B=16, d=512, H=8 (dh=64), L=4, dff=2048, Lenc=2048, 16 steps, vocab=256.
// Round 11: round-10 structure + S5 rewrite (head-broadcast lanes, q in
//   registers, in-wave reductions, swizzled 520-padded encL => 8x less enc
//   LDS traffic and no scalar q reads), single-pass LN, faster barrier poll.
// ---------------------------------------------------------------------------

typedef unsigned short ushort_t;
typedef __attribute__((ext_vector_type(4))) float f32x4;
typedef __attribute__((ext_vector_type(8))) unsigned short us8;
typedef __attribute__((ext_vector_type(4))) unsigned short us4;

#define NB 256
#define NTHR 1024

__device__ __forceinline__ float bf2f(ushort_t u) {
    union { unsigned int i; float f; } v; v.i = ((unsigned int)u) << 16; return v.f;
}
__device__ __forceinline__ ushort_t f2bf(float f) {
    union { unsigned int i; float f; } v; v.f = f;
    return (ushort_t)((v.i + 0x7FFF + ((v.i >> 16) & 1)) >> 16);   // RNE
}
__device__ __forceinline__ float wave_sum(float v) {
    #pragma unroll
    for (int m = 32; m; m >>= 1) v += __shfl_xor(v, m);
    return v;
}
__device__ __forceinline__ float wave_max(float v) {
    #pragma unroll
    for (int m = 32; m; m >>= 1) v = fmaxf(v, __shfl_xor(v, m));
    return v;
}

// ---- coherent (agent-scope, fence-free) access for mutable activations -----
union U64C { unsigned long long u; float2 f; };
__device__ __forceinline__ float clf(const float* p) {
    return __hip_atomic_load(p, __ATOMIC_RELAXED, __HIP_MEMORY_SCOPE_AGENT);
}
__device__ __forceinline__ void csf(float* p, float v) {
    __hip_atomic_store(p, v, __ATOMIC_RELAXED, __HIP_MEMORY_SCOPE_AGENT);
}
__device__ __forceinline__ float2 clf2(const float* p) {
    U64C c; c.u = __hip_atomic_load((unsigned long long*)p, __ATOMIC_RELAXED,
                                    __HIP_MEMORY_SCOPE_AGENT);
    return c.f;
}
__device__ __forceinline__ void csf2(float* p, float x, float y) {
    U64C c; c.f.x = x; c.f.y = y;
    __hip_atomic_store((unsigned long long*)p, c.u, __ATOMIC_RELAXED,
                       __HIP_MEMORY_SCOPE_AGENT);
}

// ---- fence-free PER-GROUP barrier (16 blocks, relaxed-only) -----------------
__device__ __forceinline__ void gbar(unsigned* bar, int g) {
    __syncthreads();
    if (threadIdx.x == 0) {
        unsigned* cnt = bar + g * 32;
        unsigned* rel = bar + 512 + g * 32;
        unsigned a = __hip_atomic_fetch_add(cnt, 1u, __ATOMIC_RELAXED,
                                            __HIP_MEMORY_SCOPE_AGENT);
        unsigned e = (a >> 4) + 1u;
        if ((a & 15u) == 15u) {
            __hip_atomic_store(rel, e, __ATOMIC_RELAXED, __HIP_MEMORY_SCOPE_AGENT);
        } else {
            while ((int)(__hip_atomic_load(rel, __ATOMIC_RELAXED,
                                           __HIP_MEMORY_SCOPE_AGENT) - e) < 0)
                __builtin_amdgcn_s_sleep(1);
        }
    }
    __syncthreads();
}

// ---- block-wide LN, single pass (sum+sumsq together); red needs 32 floats --
__device__ __forceinline__ void ln512b(const float* __restrict__ row,
                                       const float* __restrict__ g,
                                       const float* __restrict__ be,
                                       int use_ln, float* dst, float* red) {
    int tid = threadIdx.x;
    float a = (tid < 512) ? clf(row + tid) : 0.f;
    if (use_ln) {
        float s = a, s2 = a * a;
        #pragma unroll
        for (int m = 32; m; m >>= 1) {
            s  += __shfl_xor(s, m);
            s2 += __shfl_xor(s2, m);
        }
        if ((tid & 63) == 0) { red[tid >> 6] = s; red[16 + (tid >> 6)] = s2; }
        __syncthreads();
        float ts = 0.f, ts2 = 0.f;
        #pragma unroll
        for (int i = 0; i < 8; i++) { ts += red[i]; ts2 += red[16 + i]; }
        float mu = ts * (1.f / 512.f);
        float var = ts2 * (1.f / 512.f) - mu * mu;
        float rstd = rsqrtf(var + 1e-6f);
        if (tid < 512) dst[tid] = (a - mu) * rstd * g[tid] + be[tid];
    } else {
        if (tid < 512) dst[tid] = a;
    }
    __syncthreads();
}

// ---- all-thread split-K GEMV: NC=NCQ*4 cols, in-wave shfl reduce -----------
template<int NCQ, int K>
__device__ __forceinline__ void gemv_all(const float* xs, const float* __restrict__ W,
                                         int ldw, int col0, float* part) {
    constexpr int S = 1024 / NCQ;
    constexpr int KS = K / S;
    int tid = threadIdx.x;
    int cq = tid & (NCQ - 1), ks = tid / NCQ;
    const float* Wp = W + (size_t)(ks * KS) * ldw + col0 + cq * 4;
    const float* xp = xs + ks * KS;
    f32x4 acc = {0.f, 0.f, 0.f, 0.f};
    #pragma unroll
    for (int r = 0; r < KS; r++)
        acc += xp[r] * *(const f32x4*)(Wp + (size_t)r * ldw);
    #pragma unroll
    for (int m = NCQ; m < 64; m <<= 1) {
        acc[0] += __shfl_xor(acc[0], m);
        acc[1] += __shfl_xor(acc[1], m);
        acc[2] += __shfl_xor(acc[2], m);
        acc[3] += __shfl_xor(acc[3], m);
    }
    int wave = tid >> 6, lane = tid & 63;
    if (lane < NCQ) *(f32x4*)(part + (wave * NCQ + lane) * 4) = acc;
    __syncthreads();
}
template<int NCQ>
__device__ __forceinline__ float gemv_allr(const float* part) {
    float a = 0.f;
    #pragma unroll
    for (int w = 0; w < 16; w++) a += part[w * NCQ * 4 + threadIdx.x];
    return a;
}

struct Args {
    const float *enc, *encIn, *embW, *embB, *outW, *outB;
    const float *selfW, *selfB, *crossW, *crossB;
    const float *fW1, *fb1, *fW2, *fb2, *lng, *lnb;
    float* out;
    unsigned* bar;
    float *x0, *qbuf, *y1, *y2, *y3, *attnb;
    float *lny1, *lny2, *qt, *Pm2, *Ps2, *Pz, *tmpb, *selfK, *selfV;
};

// ---------------------------------------------------------------------------

__global__ __launch_bounds__(NTHR, 1) void k_mega(Args A) {
    // encL: [128 keys][520 shorts], element (key, d) with d = dq*64 + c*8 + j
    // stored at key*520 + dq*64 + ((c+dq)&7)*8 + j   (rotation swizzle)
    __shared__ ushort_t encL[128 * 520];   // 133120 B — persistent
    __shared__ float padL[128];
    __shared__ float sm[6400];             // 25.6 KB stage scratch
    const int bid = blockIdx.x, tid = threadIdx.x;
    const int b = bid >> 4, r = bid & 15;
    unsigned* bar = A.bar;

    // ---------------- P0: enc->LDS (padded+swizzled) + pad flags ----------
    {
        const float* ep = A.enc + ((size_t)b * 2048 + r * 128) * 512;
        #pragma unroll 4
        for (int it = 0; it < 16; it++) {
            int idx = tid + it * 1024;            // us4-chunk id < 16384
            int key = idx >> 7;
            int d = (idx & 127) * 4;
            int dq = d >> 6, cch = (d >> 3) & 7, lo = d & 7;
            int phys = key * 520 + dq * 64 + ((cch + dq) & 7) * 8 + lo;
            float4 v = *(const float4*)(ep + (size_t)key * 512 + d);
            us4 o; o[0] = f2bf(v.x); o[1] = f2bf(v.y); o[2] = f2bf(v.z); o[3] = f2bf(v.w);
            *(us4*)(encL + phys) = o;
        }
        int key = tid >> 3, sub = tid & 7;
        const float* p = A.encIn + ((size_t)b * 2048 + r * 128 + key) * 128 + sub * 16;
        int ok = 1;
        #pragma unroll
        for (int j = 0; j < 4; j++) {
            float4 v = *(const float4*)(p + j * 4);
            ok &= (v.x == 0.f) & (v.y == 0.f) & (v.z == 0.f) & (v.w == 0.f);
        }
        ok &= __shfl_xor(ok, 1); ok &= __shfl_xor(ok, 2); ok &= __shfl_xor(ok, 4);
        if (sub == 0) padL[key] = ok ? 1.f : 0.f;
    }
    __syncthreads();

    for (int t = 0; t < 16; t++) {
        // ---------------- S_emb: x0 slice (32 cols/role) -------------------
        {
            float* tok = sm;            // 256
            float* part = sm + 256;     // 512
            if (tid < 256)
                tok[tid] = (t == 0) ? 1.f
                         : clf(A.out + (size_t)b * 4096 + (t - 1) * 256 + tid);
            __syncthreads();
            gemv_all<8, 256>(tok, A.embW, 512, r * 32, part);
            if (tid < 32) {
                float acc = gemv_allr<8>(part);
                int col = r * 32 + tid;
                float expo = (2.0f * (float)(col >> 1)) * (1.f / 512.f);
                float ang = (float)t * powf(10000.0f, -expo);
                float pv = (col & 1) ? cosf(ang) : sinf(ang);
                csf(A.x0 + (size_t)b * 512 + col,
                    (acc + A.embB[col]) * 22.627416997969522f + pv);
            }
        }
        gbar(bar, b);

        for (int l = 0; l < 4; l++) {
            const float* src = (l == 0) ? A.x0 : A.y3;
            const float* gP = (l == 0) ? nullptr : A.lng + ((l - 1) * 3 + 2) * 512;
            const float* bP = (l == 0) ? nullptr : A.lnb + ((l - 1) * 3 + 2) * 512;
            int ulnP = (l != 0);

            // ------------ S1: q/k/v fused triple GEMV (32 cols each) -------
            {
                float* xs = sm;            // 512
                float* red = sm + 512;     // 32
                float* part = sm + 1024;   // 3*512
                ln512b(src + (size_t)b * 512, gP, bP, ulnP, xs, red);
                int cq = tid & 7, ks = tid >> 3;         // 128 slices of 4
                const float* xp = xs + ks * 4;
                f32x4 a0 = {0.f,0.f,0.f,0.f}, a1 = a0, a2 = a0;
                const float* W0 = A.selfW + ((size_t)(l * 4 + 0)) * 262144
                                + (size_t)(ks * 4) * 512 + r * 32 + cq * 4;
                const float* W1 = W0 + 262144;
                const float* W2 = W1 + 262144;
                #pragma unroll
                for (int rr = 0; rr < 4; rr++) {
                    float x = xp[rr];
                    a0 += x * *(const f32x4*)(W0 + (size_t)rr * 512);
                    a1 += x * *(const f32x4*)(W1 + (size_t)rr * 512);
                    a2 += x * *(const f32x4*)(W2 + (size_t)rr * 512);
                }
                #pragma unroll
                for (int m = 8; m < 64; m <<= 1) {
                    #pragma unroll
                    for (int j = 0; j < 4; j++) {
                        a0[j] += __shfl_xor(a0[j], m);
                        a1[j] += __shfl_xor(a1[j], m);
                        a2[j] += __shfl_xor(a2[j], m);
                    }
                }
                int wave = tid >> 6, lane = tid & 63;
                if (lane < 8) {
                    *(f32x4*)(part + (wave * 8 + lane) * 4) = a0;
                    *(f32x4*)(part + 512 + (wave * 8 + lane) * 4) = a1;
                    *(f32x4*)(part + 1024 + (wave * 8 + lane) * 4) = a2;
                }
                __syncthreads();
                if (tid < 96) {
                    int m = tid >> 5, j = tid & 31;
                    float a = 0.f;
                    #pragma unroll
                    for (int w = 0; w < 16; w++) a += part[m * 512 + w * 32 + j];
                    int col = r * 32 + j;
                    a += A.selfB[(l * 4 + m) * 512 + col];
                    if (m == 0) csf(A.qbuf + (size_t)b * 512 + col, a);
                    else if (m == 1)
                        csf(A.selfK + (((size_t)l * 16 + b) * 16 + t) * 512 + col, a);
                    else
                        csf(A.selfV + (((size_t)l * 16 + b) * 16 + t) * 512 + col, a);
                }
            }
            gbar(bar, b);

            // ------------ S2: self-attn + Wo slice + residual --------------
            {
                float* xr = sm;            // 512
                float* qs = sm + 512;      // 512 (later reused for AV result)
                float* as2 = sm + 1024;    // 1024
                float* lg = sm + 2048;     // 128
                float* red = sm + 2176;    // 32
                float* part = sm + 2560;   // 512
                ln512b(src + (size_t)b * 512, gP, bP, ulnP, xr, red);
                if (tid < 256) {
                    float2 v = clf2(A.qbuf + (size_t)b * 512 + tid * 2);
                    qs[tid * 2] = v.x; qs[tid * 2 + 1] = v.y;
                }
                __syncthreads();
                const float* Kb = A.selfK + ((size_t)l * 16 + b) * 16 * 512;
                const float* Vb = A.selfV + ((size_t)l * 16 + b) * 16 * 512;
                if (tid < 512) {
                    int idx = tid >> 2, q4 = tid & 3;
                    int h = idx >> 4, j = idx & 15;
                    if (j <= t) {
                        const float* kp = Kb + (size_t)j * 512 + h * 64 + q4 * 16;
                        const float* qp = qs + h * 64 + q4 * 16;
                        float s = 0.f;
                        #pragma unroll
                        for (int d = 0; d < 16; d += 2) {
                            float2 kv = clf2(kp + d);
                            s += qp[d] * kv.x + qp[d + 1] * kv.y;
                        }
                        s += __shfl_xor(s, 1);
                        s += __shfl_xor(s, 2);
                        if (q4 == 0) lg[h * 16 + j] = s * 0.125f;
                    }
                }
                __syncthreads();
                if (tid < 8) {
                    float m = -1e30f;
                    for (int j = 0; j <= t; j++) m = fmaxf(m, lg[tid * 16 + j]);
                    float ssum = 0.f;
                    for (int j = 0; j <= t; j++) {
                        float e = __expf(lg[tid * 16 + j] - m);
                        lg[tid * 16 + j] = e; ssum += e;
                    }
                    float inv = 1.f / ssum;
                    for (int j = 0; j <= t; j++) lg[tid * 16 + j] *= inv;
                }
                __syncthreads();
                {   // AV on all 1024 threads (j parity split)
                    int col = tid & 511, jh = tid >> 9;
                    float a = 0.f;
                    for (int j = jh; j <= t; j += 2)
                        a += lg[(col >> 6) * 16 + j] * clf(Vb + (size_t)j * 512 + col);
                    as2[jh * 512 + col] = a;
                }
                __syncthreads();
                if (tid < 512) qs[tid] = as2[tid] + as2[512 + tid];
                __syncthreads();
                gemv_all<8, 512>(qs, A.selfW + ((size_t)(l * 4 + 3)) * 262144,
                                 512, r * 32, part);
                if (tid < 32) {
                    int col = r * 32 + tid;
                    csf(A.y1 + (size_t)b * 512 + col,
                        gemv_allr<8>(part) + A.selfB[(l * 4 + 3) * 512 + col] + xr[col]);
                }
            }
            gbar(bar, b);

            // ------------ S34: qc_h (redundant per half) + qt_h half -------
            {
                int h = r >> 1, half = r & 1;
                float* xsw = sm;           // 512
                float* red = sm + 512;     // 32
                float* qch = sm + 544;     // 64
                float* part = sm + 1024;   // 1024 (NCQ=16)
                ln512b(A.y1 + (size_t)b * 512, A.lng + (l * 3) * 512,
                       A.lnb + (l * 3) * 512, 1, xsw, red);
                if (r == 0 && tid < 512)
                    csf(A.lny1 + (size_t)b * 512 + tid, xsw[tid]);
                gemv_all<16, 512>(xsw, A.crossW + ((size_t)(l * 4)) * 262144,
                                  512, h * 64, part);
                if (tid < 64)
                    qch[tid] = gemv_allr<16>(part)
                             + A.crossB[(l * 4) * 512 + h * 64 + tid];
                __syncthreads();
                {   // qt[b,h,D-half] = 0.125 * qch . Wk[D][h*64..]
                    int D = half * 256 + (tid >> 2), q4 = tid & 3;
                    const float* wr = A.crossW + ((size_t)(l * 4 + 1)) * 262144
                                    + (size_t)D * 512 + h * 64 + q4 * 16;
                    const float* qp = qch + q4 * 16;
                    float a = 0.f;
                    #pragma unroll
                    for (int j = 0; j < 16; j += 4) {
                        f32x4 wv = *(const f32x4*)(wr + j);
                        a += qp[j]*wv[0] + qp[j+1]*wv[1] + qp[j+2]*wv[2] + qp[j+3]*wv[3];
                    }
                    a += __shfl_xor(a, 1);
                    a += __shfl_xor(a, 2);
                    if (q4 == 0)
                        csf(A.qt + ((size_t)b * 8 + h) * 512 + D, a * 0.125f);
                }
            }
            gbar(bar, b);

            // ------------ S5: flash cross-attn (head-broadcast layout) -----
            {
                float* qts3 = sm;           // 64*68 = 4352 (lane-linear q)
                float* lge  = sm + 4352;    // 8*132 = 1056
                float* wms  = sm + 5440;    // 16
                float* wss  = sm + 5456;    // 16
                // stage qt -> qts3[(dq*8+hh)*68 + c*8 + j]
                #pragma unroll
                for (int it = 0; it < 2; it++) {
                    int p = tid + it * 1024;            // pair index < 2048
                    float2 v = clf2(A.qt + (size_t)b * 4096 + p * 2);
                    int e0 = p * 2;
                    int hh = e0 >> 9, D = e0 & 511;
                    int dq = D >> 6, c = (D >> 3) & 7, j = D & 7;
                    float* dst = qts3 + (dq * 8 + hh) * 68 + c * 8 + j;
                    dst[0] = v.x; dst[1] = v.y;
                }
                __syncthreads();
                // phase A: logits. thread = (ko 16, dq 8, hh 8); hh lanes
                // broadcast enc reads; reduce over dq in-wave.
                {
                    int ko = tid >> 6, dq = (tid >> 3) & 7;
                    int lane = tid & 63;
                    const float* qb = qts3 + lane * 68;
                    f32x4 q4[16];
                    #pragma unroll
                    for (int c = 0; c < 8; c++) {
                        q4[2 * c]     = *(const f32x4*)(qb + c * 8);
                        q4[2 * c + 1] = *(const f32x4*)(qb + c * 8 + 4);
                    }
                    float a[8];
                    #pragma unroll
                    for (int ki = 0; ki < 8; ki++) a[ki] = 0.f;
                    #pragma unroll
                    for (int ki = 0; ki < 8; ki++) {
                        int key = ko * 8 + ki;
                        const ushort_t* er = encL + key * 520 + dq * 64;
                        #pragma unroll
                        for (int c = 0; c < 8; c++) {
                            us8 e = *(const us8*)(er + ((c + dq) & 7) * 8);
                            a[ki] += q4[2*c][0]*bf2f(e[0]) + q4[2*c][1]*bf2f(e[1])
                                   + q4[2*c][2]*bf2f(e[2]) + q4[2*c][3]*bf2f(e[3])
                                   + q4[2*c+1][0]*bf2f(e[4]) + q4[2*c+1][1]*bf2f(e[5])
                                   + q4[2*c+1][2]*bf2f(e[6]) + q4[2*c+1][3]*bf2f(e[7]);
                        }
                    }
                    #pragma unroll
                    for (int ki = 0; ki < 8; ki++) {
                        a[ki] += __shfl_xor(a[ki], 8);
                        a[ki] += __shfl_xor(a[ki], 16);
                        a[ki] += __shfl_xor(a[ki], 32);
                    }
                    if (dq == 0) {
                        int hh = tid & 7;
                        #pragma unroll
                        for (int ki = 0; ki < 8; ki++) {
                            int key = ko * 8 + ki;
                            lge[hh * 132 + key] = (padL[key] != 0.f) ? -2e30f : a[ki];
                        }
                    }
                }
                __syncthreads();
                // phase B: softmax over 128 keys (wave = half a head)
                {
                    int hh = tid >> 7, k = tid & 127;
                    float lv = lge[hh * 132 + k];
                    float mv = wave_max(lv);
                    if ((tid & 63) == 0) wms[tid >> 6] = mv;
                    __syncthreads();
                    float m = fmaxf(wms[hh * 2], wms[hh * 2 + 1]);
                    float ev = __expf(lv - m);
                    float sv = wave_sum(ev);
                    if ((tid & 63) == 0) wss[tid >> 6] = sv;
                    lge[hh * 132 + k] = ev;
                    __syncthreads();
                    if (tid < 8) {
                        int bc = b * 16 + r;
                        csf(A.Pm2 + bc * 8 + tid, fmaxf(wms[tid * 2], wms[tid * 2 + 1]));
                        csf(A.Ps2 + bc * 8 + tid, wss[tid * 2] + wss[tid * 2 + 1]);
                    }
                }
                __syncthreads();
                // phase C: z. thread = (ii8 64, kh 2, hz 8); hz lanes
                // broadcast enc; reduce over kh in-wave (lane bit 3).
                {
                    int ii8 = tid >> 4, kh = (tid >> 3) & 1, hz = tid & 7;
                    int dq = ii8 >> 3, c = ii8 & 7;
                    const ushort_t* ep2 = encL + dq * 64 + ((c + dq) & 7) * 8;
                    const float* le = lge + hz * 132 + kh * 64;
                    f32x4 z0 = {0.f,0.f,0.f,0.f}, z1 = z0;
                    #pragma unroll 4
                    for (int k4 = 0; k4 < 16; k4++) {
                        f32x4 ev4 = *(const f32x4*)(le + k4 * 4);
                        #pragma unroll
                        for (int j = 0; j < 4; j++) {
                            int key = kh * 64 + k4 * 4 + j;
                            us8 e = *(const us8*)(ep2 + key * 520);
                            float ev = ev4[j];
                            z0[0] += ev * bf2f(e[0]); z0[1] += ev * bf2f(e[1]);
                            z0[2] += ev * bf2f(e[2]); z0[3] += ev * bf2f(e[3]);
                            z1[0] += ev * bf2f(e[4]); z1[1] += ev * bf2f(e[5]);
                            z1[2] += ev * bf2f(e[6]); z1[3] += ev * bf2f(e[7]);
                        }
                    }
                    #pragma unroll
                    for (int j = 0; j < 4; j++) {
                        z0[j] += __shfl_xor(z0[j], 8);
                        z1[j] += __shfl_xor(z1[j], 8);
                    }
                    if (kh == 0) {
                        float* dst = A.Pz + ((size_t)((b * 16 + r) * 8 + hz)) * 512 + ii8 * 8;
                        csf2(dst,     z0[0], z0[1]);
                        csf2(dst + 2, z0[2], z0[3]);
                        csf2(dst + 4, z1[0], z1[1]);
                        csf2(dst + 6, z1[2], z1[3]);
                    }
                }
            }
            gbar(bar, b);

            // ------------ S6: combine chunks + Wv slice --------------------
            {
                int h = r >> 1, half = r & 1;
                float* zs = sm;            // 512
                float* zs2 = sm + 512;     // 2048 (4 quarters)
                float* ecs = sm + 2560;    // 17
                float* part = sm + 2624;   // 512
                if (tid < 16) {
                    float mcv = clf(A.Pm2 + (b * 16 + tid) * 8 + h);
                    float mm = mcv;
                    mm = fmaxf(mm, __shfl_xor(mm, 1));
                    mm = fmaxf(mm, __shfl_xor(mm, 2));
                    mm = fmaxf(mm, __shfl_xor(mm, 4));
                    mm = fmaxf(mm, __shfl_xor(mm, 8));
                    float ec = __expf(mcv - mm);
                    float sv = ec * clf(A.Ps2 + (b * 16 + tid) * 8 + h);
                    sv += __shfl_xor(sv, 1); sv += __shfl_xor(sv, 2);
                    sv += __shfl_xor(sv, 4); sv += __shfl_xor(sv, 8);
                    ecs[tid] = ec;
                    if (tid == 0) ecs[16] = 1.f / sv;
                }
                __syncthreads();
                {   // 4 quarters x 256 col-pairs, clf2 loads
                    int cp = (tid & 255) * 2, qtr = tid >> 8;
                    float a0 = 0.f, a1 = 0.f;
                    #pragma unroll
                    for (int j = 0; j < 4; j++) {
                        int cc = qtr * 4 + j;
                        float2 v = clf2(A.Pz + ((size_t)(b * 16 + cc) * 8 + h) * 512 + cp);
                        a0 += ecs[cc] * v.x; a1 += ecs[cc] * v.y;
                    }
                    zs2[qtr * 512 + cp] = a0;
                    zs2[qtr * 512 + cp + 1] = a1;
                }
                __syncthreads();
                if (tid < 512)
                    zs[tid] = (zs2[tid] + zs2[512 + tid] + zs2[1024 + tid]
                             + zs2[1536 + tid]) * ecs[16];
                __syncthreads();
                gemv_all<8, 512>(zs, A.crossW + ((size_t)(l * 4 + 2)) * 262144,
                                 512, h * 64 + half * 32, part);
                if (tid < 32) {
                    int col = h * 64 + half * 32 + tid;
                    csf(A.attnb + (size_t)b * 512 + col,
                        gemv_allr<8>(part) + A.crossB[(l * 4 + 2) * 512 + col]);
                }
            }
            gbar(bar, b);

            // ------------ S7: y2 slice = attnb@Wco + bco + lny1 ------------
            {
                float* xa = sm;            // 512
                float* part = sm + 512;    // 512
                if (tid < 256) {
                    float2 v = clf2(A.attnb + (size_t)b * 512 + tid * 2);
                    xa[tid * 2] = v.x; xa[tid * 2 + 1] = v.y;
                }
                __syncthreads();
                gemv_all<8, 512>(xa, A.crossW + ((size_t)(l * 4 + 3)) * 262144,
                                 512, r * 32, part);
                if (tid < 32) {
                    int col = r * 32 + tid;
                    csf(A.y2 + (size_t)b * 512 + col,
                        gemv_allr<8>(part) + A.crossB[(l * 4 + 3) * 512 + col]
                        + clf(A.lny1 + (size_t)b * 512 + col));
                }
            }
            gbar(bar, b);

            // ------------ S8: tmpb slice (128 cols) = relu(LN(y2)@W1) ------
            {
                float* xsw = sm;           // 512
                float* red = sm + 512;     // 32
                float* part = sm + 1024;   // 2048 (NCQ=32)
                ln512b(A.y2 + (size_t)b * 512, A.lng + (l * 3 + 1) * 512,
                       A.lnb + (l * 3 + 1) * 512, 1, xsw, red);
                if (r == 0 && tid < 512)
                    csf(A.lny2 + (size_t)b * 512 + tid, xsw[tid]);
                gemv_all<32, 512>(xsw, A.fW1 + (size_t)l * 512 * 2048,
                                  2048, r * 128, part);
                if (tid < 128) {
                    int col = r * 128 + tid;
                    csf(A.tmpb + (size_t)b * 2048 + col,
                        fmaxf(gemv_allr<32>(part) + A.fb1[l * 2048 + col], 0.f));
                }
            }
            gbar(bar, b);

            // ------------ S9: y3 slice = tmpb@W2 + b2 + lny2 ---------------
            {
                float* ts = sm;            // 2048
                float* part = sm + 2048;   // 512
                {
                    float2 v = clf2(A.tmpb + (size_t)b * 2048 + tid * 2);
                    ts[tid * 2] = v.x; ts[tid * 2 + 1] = v.y;
                }
                __syncthreads();
                gemv_all<8, 2048>(ts, A.fW2 + (size_t)l * 2048 * 512,
                                  512, r * 32, part);
                if (tid < 32) {
                    int col = r * 32 + tid;
                    csf(A.y3 + (size_t)b * 512 + col,
                        gemv_allr<8>(part) + A.fb2[l * 512 + col]
                        + clf(A.lny2 + (size_t)b * 512 + col));
                }
            }
            gbar(bar, b);
        } // l

        // ---------------- S_out: logits slice (16 cols/role) ---------------
        {
            float* xsw = sm;           // 512
            float* red = sm + 512;     // 32
            float* part = sm + 1024;   // 256 (NCQ=4)
            ln512b(A.y3 + (size_t)b * 512, A.lng + 11 * 512, A.lnb + 11 * 512,
                   1, xsw, red);
            gemv_all<4, 512>(xsw, A.outW, 256, r * 16, part);
            if (tid < 16) {
                int col = r * 16 + tid;
                csf(A.out + (size_t)b * 4096 + t * 256 + col,
                    gemv_allr<4>(part) + A.outB[col]);
            }
        }
        gbar(bar, b);
    } // t
}

// ---------------------------------------------------------------------------

extern "C" void kernel_launch(void* const* d_in, const int* in_sizes, int n_in,
                              void* d_out, int out_size, void* d_ws, size_t ws_size,
                              hipStream_t stream) {
    Args A;
    A.enc    = (const float*)d_in[0];
    A.encIn  = (const float*)d_in[1];
    A.embW   = (const float*)d_in[2];
    A.embB   = (const float*)d_in[3];
    A.outW   = (const float*)d_in[4];
    A.outB   = (const float*)d_in[5];
    A.selfW  = (const float*)d_in[6];
    A.selfB  = (const float*)d_in[7];
    A.crossW = (const float*)d_in[8];
    A.crossB = (const float*)d_in[9];
    A.fW1    = (const float*)d_in[10];
    A.fb1    = (const float*)d_in[11];
    A.fW2    = (const float*)d_in[12];
    A.fb2    = (const float*)d_in[13];
    A.lng    = (const float*)d_in[14];
    A.lnb    = (const float*)d_in[15];
    A.out    = (float*)d_out;

    char* ws = (char*)d_ws;
    size_t off = 0;
    auto alloc = [&](size_t bytes) -> char* {
        char* p = ws + off;
        off = (off + bytes + 255) & ~(size_t)255;
        return p;
    };
    char* barrier = alloc(4096);
    A.bar = (unsigned*)barrier;
    A.x0    = (float*)alloc(16 * 512 * 4);
    A.qbuf  = (float*)alloc(16 * 512 * 4);
    A.y1    = (float*)alloc(16 * 512 * 4);
    A.y2    = (float*)alloc(16 * 512 * 4);
    A.y3    = (float*)alloc(16 * 512 * 4);
    A.attnb = (float*)alloc(16 * 512 * 4);
    A.lny1  = (float*)alloc(16 * 512 * 4);
    A.lny2  = (float*)alloc(16 * 512 * 4);
    A.qt    = (float*)alloc((size_t)16 * 8 * 512 * 4);
    A.Pm2   = (float*)alloc(16 * 16 * 8 * 4);
    A.Ps2   = (float*)alloc(16 * 16 * 8 * 4);
    A.Pz    = (float*)alloc((size_t)16 * 16 * 8 * 512 * 4);
    A.tmpb  = (float*)alloc((size_t)16 * 2048 * 4);
    A.selfK = (float*)alloc((size_t)4 * 16 * 16 * 512 * 4);
    A.selfV = (float*)alloc((size_t)4 * 16 * 16 * 512 * 4);
    if (off > ws_size) return;   // ~9 MB — always fits

    hipMemsetAsync(barrier, 0, 4096, stream);
    k_mega<<<dim3(NB), dim3(NTHR), 0, stream>>>(A);
}

// Round 12
// 4996.618 us; speedup vs baseline: 2.7779x; 2.7779x over previous
//
#include <hip/hip_runtime.h>

// ---------------------------------------------------------------------------
// Decoder_49005576847865 — persistent decoder, independent batch groups.
//   B=16, d=512, H=8 (dh=64), L=4, dff=2048, Lenc=2048, 16 steps, vocab=256.
// Round 12: revert to round-10 structure (5.12ms proven; round 11's S5
//   register-cache spilled to scratch => 30GB HBM traffic). Keep only the
//   verified-cheap round-11 pieces: encL rows padded to 520 shorts (breaks
//   32-bank key-stride aliasing), single-pass LN, s_sleep(1) barrier poll,
//   launch_bounds(1024,4).
// ---------------------------------------------------------------------------

typedef unsigned short ushort_t;
typedef __attribute__((ext_vector_type(4))) float f32x4;
typedef __attribute__((ext_vector_type(8))) unsigned short us8;
typedef __attribute__((ext_vector_type(4))) unsigned short us4;

#define NB 256
#define NTHR 1024

__device__ __forceinline__ float bf2f(ushort_t u) {
    union { unsigned int i; float f; } v; v.i = ((unsigned int)u) << 16; return v.f;
}
__device__ __forceinline__ ushort_t f2bf(float f) {
    union { unsigned int i; float f; } v; v.f = f;
    return (ushort_t)((v.i + 0x7FFF + ((v.i >> 16) & 1)) >> 16);   // RNE
}
__device__ __forceinline__ float wave_sum(float v) {
    #pragma unroll
    for (int m = 32; m; m >>= 1) v += __shfl_xor(v, m);
    return v;
}
__device__ __forceinline__ float wave_max(float v) {
    #pragma unroll
    for (int m = 32; m; m >>= 1) v = fmaxf(v, __shfl_xor(v, m));
    return v;
}

// ---- coherent (agent-scope, fence-free) access for mutable activations -----
union U64C { unsigned long long u; float2 f; };
__device__ __forceinline__ float clf(const float* p) {
    return __hip_atomic_load(p, __ATOMIC_RELAXED, __HIP_MEMORY_SCOPE_AGENT);
}
__device__ __forceinline__ void csf(float* p, float v) {
    __hip_atomic_store(p, v, __ATOMIC_RELAXED, __HIP_MEMORY_SCOPE_AGENT);
}
__device__ __forceinline__ float2 clf2(const float* p) {
    U64C c; c.u = __hip_atomic_load((unsigned long long*)p, __ATOMIC_RELAXED,
                                    __HIP_MEMORY_SCOPE_AGENT);
    return c.f;
}
__device__ __forceinline__ void csf2(float* p, float x, float y) {
    U64C c; c.f.x = x; c.f.y = y;
    __hip_atomic_store((unsigned long long*)p, c.u, __ATOMIC_RELAXED,
                       __HIP_MEMORY_SCOPE_AGENT);
}

// ---- fence-free PER-GROUP barrier (16 blocks, relaxed-only) -----------------
__device__ __forceinline__ void gbar(unsigned* bar, int g) {
    __syncthreads();
    if (threadIdx.x == 0) {
        unsigned* cnt = bar + g * 32;
        unsigned* rel = bar + 512 + g * 32;
        unsigned a = __hip_atomic_fetch_add(cnt, 1u, __ATOMIC_RELAXED,
                                            __HIP_MEMORY_SCOPE_AGENT);
        unsigned e = (a >> 4) + 1u;
        if ((a & 15u) == 15u) {
            __hip_atomic_store(rel, e, __ATOMIC_RELAXED, __HIP_MEMORY_SCOPE_AGENT);
        } else {
            while ((int)(__hip_atomic_load(rel, __ATOMIC_RELAXED,
                                           __HIP_MEMORY_SCOPE_AGENT) - e) < 0)
                __builtin_amdgcn_s_sleep(1);
        }
    }
    __syncthreads();
}

// ---- block-wide LN, single pass (sum+sumsq); red needs 32 floats -----------
__device__ __forceinline__ void ln512b(const float* __restrict__ row,
                                       const float* __restrict__ g,
                                       const float* __restrict__ be,
                                       int use_ln, float* dst, float* red) {
    int tid = threadIdx.x;
    float a = (tid < 512) ? clf(row + tid) : 0.f;
    if (use_ln) {
        float s = a, s2 = a * a;
        #pragma unroll
        for (int m = 32; m; m >>= 1) {
            s  += __shfl_xor(s, m);
            s2 += __shfl_xor(s2, m);
        }
        if ((tid & 63) == 0) { red[tid >> 6] = s; red[16 + (tid >> 6)] = s2; }
        __syncthreads();
        float ts = 0.f, ts2 = 0.f;
        #pragma unroll
        for (int i = 0; i < 8; i++) { ts += red[i]; ts2 += red[16 + i]; }
        float mu = ts * (1.f / 512.f);
        float var = ts2 * (1.f / 512.f) - mu * mu;
        float rstd = rsqrtf(var + 1e-6f);
        if (tid < 512) dst[tid] = (a - mu) * rstd * g[tid] + be[tid];
    } else {
        if (tid < 512) dst[tid] = a;
    }
    __syncthreads();
}

// ---- all-thread split-K GEMV: NC=NCQ*4 cols, in-wave shfl reduce -----------
template<int NCQ, int K>
__device__ __forceinline__ void gemv_all(const float* xs, const float* __restrict__ W,
                                         int ldw, int col0, float* part) {
    constexpr int S = 1024 / NCQ;
    constexpr int KS = K / S;
    int tid = threadIdx.x;
    int cq = tid & (NCQ - 1), ks = tid / NCQ;
    const float* Wp = W + (size_t)(ks * KS) * ldw + col0 + cq * 4;
    const float* xp = xs + ks * KS;
    f32x4 acc = {0.f, 0.f, 0.f, 0.f};
    #pragma unroll
    for (int r = 0; r < KS; r++)
        acc += xp[r] * *(const f32x4*)(Wp + (size_t)r * ldw);
    #pragma unroll
    for (int m = NCQ; m < 64; m <<= 1) {
        acc[0] += __shfl_xor(acc[0], m);
        acc[1] += __shfl_xor(acc[1], m);
        acc[2] += __shfl_xor(acc[2], m);
        acc[3] += __shfl_xor(acc[3], m);
    }
    int wave = tid >> 6, lane = tid & 63;
    if (lane < NCQ) *(f32x4*)(part + (wave * NCQ + lane) * 4) = acc;
    __syncthreads();
}
template<int NCQ>
__device__ __forceinline__ float gemv_allr(const float* part) {
    float a = 0.f;
    #pragma unroll
    for (int w = 0; w < 16; w++) a += part[w * NCQ * 4 + threadIdx.x];
    return a;
}

struct Args {
    const float *enc, *encIn, *embW, *embB, *outW, *outB;
    const float *selfW, *selfB, *crossW, *crossB;
    const float *fW1, *fb1, *fW2, *fb2, *lng, *lnb;
    float* out;
    unsigned* bar;
    float *x0, *qbuf, *y1, *y2, *y3, *attnb;
    float *lny1, *lny2, *qt, *Pm2, *Ps2, *Pz, *tmpb, *selfK, *selfV;
};

// ---------------------------------------------------------------------------

__global__ __launch_bounds__(NTHR, 4) void k_mega(Args A) {
    __shared__ ushort_t encL[128 * 520];   // 520-padded rows (133120 B)
    __shared__ float padL[128];
    __shared__ float sm[6400];             // 25.6 KB stage scratch
    const int bid = blockIdx.x, tid = threadIdx.x;
    const int b = bid >> 4, r = bid & 15;
    unsigned* bar = A.bar;

    // ---------------- P0: enc->LDS (row-padded) + pad flags ----------------
    {
        const float* ep = A.enc + ((size_t)b * 2048 + r * 128) * 512;
        #pragma unroll 4
        for (int it = 0; it < 16; it++) {
            int idx = tid + it * 1024;            // us4-chunk id < 16384
            int key = idx >> 7;
            int d = (idx & 127) * 4;
            float4 v = *(const float4*)(ep + (size_t)key * 512 + d);
            us4 o; o[0] = f2bf(v.x); o[1] = f2bf(v.y); o[2] = f2bf(v.z); o[3] = f2bf(v.w);
            *(us4*)(encL + key * 520 + d) = o;
        }
        int key = tid >> 3, sub = tid & 7;
        const float* p = A.encIn + ((size_t)b * 2048 + r * 128 + key) * 128 + sub * 16;
        int ok = 1;
        #pragma unroll
        for (int j = 0; j < 4; j++) {
            float4 v = *(const float4*)(p + j * 4);
            ok &= (v.x == 0.f) & (v.y == 0.f) & (v.z == 0.f) & (v.w == 0.f);
        }
        ok &= __shfl_xor(ok, 1); ok &= __shfl_xor(ok, 2); ok &= __shfl_xor(ok, 4);
        if (sub == 0) padL[key] = ok ? 1.f : 0.f;
    }
    __syncthreads();

    for (int t = 0; t < 16; t++) {
        // ---------------- S_emb: x0 slice (32 cols/role) -------------------
        {
            float* tok = sm;            // 256
            float* part = sm + 256;     // 512
            if (tid < 256)
                tok[tid] = (t == 0) ? 1.f
                         : clf(A.out + (size_t)b * 4096 + (t - 1) * 256 + tid);
            __syncthreads();
            gemv_all<8, 256>(tok, A.embW, 512, r * 32, part);
            if (tid < 32) {
                float acc = gemv_allr<8>(part);
                int col = r * 32 + tid;
                float expo = (2.0f * (float)(col >> 1)) * (1.f / 512.f);
                float ang = (float)t * powf(10000.0f, -expo);
                float pv = (col & 1) ? cosf(ang) : sinf(ang);
                csf(A.x0 + (size_t)b * 512 + col,
                    (acc + A.embB[col]) * 22.627416997969522f + pv);
            }
        }
        gbar(bar, b);

        for (int l = 0; l < 4; l++) {
            const float* src = (l == 0) ? A.x0 : A.y3;
            const float* gP = (l == 0) ? nullptr : A.lng + ((l - 1) * 3 + 2) * 512;
            const float* bP = (l == 0) ? nullptr : A.lnb + ((l - 1) * 3 + 2) * 512;
            int ulnP = (l != 0);

            // ------------ S1: q/k/v fused triple GEMV (32 cols each) -------
            {
                float* xs = sm;            // 512
                float* red = sm + 512;     // 32
                float* part = sm + 1024;   // 3*512
                ln512b(src + (size_t)b * 512, gP, bP, ulnP, xs, red);
                int cq = tid & 7, ks = tid >> 3;         // 128 slices of 4
                const float* xp = xs + ks * 4;
                f32x4 a0 = {0.f,0.f,0.f,0.f}, a1 = a0, a2 = a0;
                const float* W0 = A.selfW + ((size_t)(l * 4 + 0)) * 262144
                                + (size_t)(ks * 4) * 512 + r * 32 + cq * 4;
                const float* W1 = W0 + 262144;
                const float* W2 = W1 + 262144;
                #pragma unroll
                for (int rr = 0; rr < 4; rr++) {
                    float x = xp[rr];
                    a0 += x * *(const f32x4*)(W0 + (size_t)rr * 512);
                    a1 += x * *(const f32x4*)(W1 + (size_t)rr * 512);
                    a2 += x * *(const f32x4*)(W2 + (size_t)rr * 512);
                }
                #pragma unroll
                for (int m = 8; m < 64; m <<= 1) {
                    #pragma unroll
                    for (int j = 0; j < 4; j++) {
                        a0[j] += __shfl_xor(a0[j], m);
                        a1[j] += __shfl_xor(a1[j], m);
                        a2[j] += __shfl_xor(a2[j], m);
                    }
                }
                int wave = tid >> 6, lane = tid & 63;
                if (lane < 8) {
                    *(f32x4*)(part + (wave * 8 + lane) * 4) = a0;
                    *(f32x4*)(part + 512 + (wave * 8 + lane) * 4) = a1;
                    *(f32x4*)(part + 1024 + (wave * 8 + lane) * 4) = a2;
                }
                __syncthreads();
                if (tid < 96) {
                    int m = tid >> 5, j = tid & 31;
                    float a = 0.f;
                    #pragma unroll
                    for (int w = 0; w < 16; w++) a += part[m * 512 + w * 32 + j];
                    int col = r * 32 + j;
                    a += A.selfB[(l * 4 + m) * 512 + col];
                    if (m == 0) csf(A.qbuf + (size_t)b * 512 + col, a);
                    else if (m == 1)
                        csf(A.selfK + (((size_t)l * 16 + b) * 16 + t) * 512 + col, a);
                    else
                        csf(A.selfV + (((size_t)l * 16 + b) * 16 + t) * 512 + col, a);
                }
            }
            gbar(bar, b);

            // ------------ S2: self-attn + Wo slice + residual --------------
            {
                float* xr = sm;            // 512
                float* qs = sm + 512;      // 512 (later reused for AV result)
                float* as2 = sm + 1024;    // 1024
                float* lg = sm + 2048;     // 128
                float* red = sm + 2176;    // 32
                float* part = sm + 2560;   // 512
                ln512b(src + (size_t)b * 512, gP, bP, ulnP, xr, red);
                if (tid < 256) {
                    float2 v = clf2(A.qbuf + (size_t)b * 512 + tid * 2);
                    qs[tid * 2] = v.x; qs[tid * 2 + 1] = v.y;
                }
                __syncthreads();
                const float* Kb = A.selfK + ((size_t)l * 16 + b) * 16 * 512;
                const float* Vb = A.selfV + ((size_t)l * 16 + b) * 16 * 512;
                if (tid < 512) {
                    int idx = tid >> 2, q4 = tid & 3;
                    int h = idx >> 4, j = idx & 15;
                    if (j <= t) {
                        const float* kp = Kb + (size_t)j * 512 + h * 64 + q4 * 16;
                        const float* qp = qs + h * 64 + q4 * 16;
                        float s = 0.f;
                        #pragma unroll
                        for (int d = 0; d < 16; d += 2) {
                            float2 kv = clf2(kp + d);
                            s += qp[d] * kv.x + qp[d + 1] * kv.y;
                        }
                        s += __shfl_xor(s, 1);
                        s += __shfl_xor(s, 2);
                        if (q4 == 0) lg[h * 16 + j] = s * 0.125f;
                    }
                }
                __syncthreads();
                if (tid < 8) {
                    float m = -1e30f;
                    for (int j = 0; j <= t; j++) m = fmaxf(m, lg[tid * 16 + j]);
                    float ssum = 0.f;
                    for (int j = 0; j <= t; j++) {
                        float e = __expf(lg[tid * 16 + j] - m);
                        lg[tid * 16 + j] = e; ssum += e;
                    }
                    float inv = 1.f / ssum;
                    for (int j = 0; j <= t; j++) lg[tid * 16 + j] *= inv;
                }
                __syncthreads();
                {   // AV on all 1024 threads (j parity split)
                    int col = tid & 511, jh = tid >> 9;
                    float a = 0.f;
                    for (int j = jh; j <= t; j += 2)
                        a += lg[(col >> 6) * 16 + j] * clf(Vb + (size_t)j * 512 + col);
                    as2[jh * 512 + col] = a;
                }
                __syncthreads();
                if (tid < 512) qs[tid] = as2[tid] + as2[512 + tid];
                __syncthreads();
                gemv_all<8, 512>(qs, A.selfW + ((size_t)(l * 4 + 3)) * 262144,
                                 512, r * 32, part);
                if (tid < 32) {
                    int col = r * 32 + tid;
                    csf(A.y1 + (size_t)b * 512 + col,
                        gemv_allr<8>(part) + A.selfB[(l * 4 + 3) * 512 + col] + xr[col]);
                }
            }
            gbar(bar, b);

            // ------------ S34: qc_h (redundant per half) + qt_h half -------
            {
                int h = r >> 1, half = r & 1;
                float* xsw = sm;           // 512
                float* red = sm + 512;     // 32
                float* qch = sm + 544;     // 64
                float* part = sm + 1024;   // 1024 (NCQ=16)
                ln512b(A.y1 + (size_t)b * 512, A.lng + (l * 3) * 512,
                       A.lnb + (l * 3) * 512, 1, xsw, red);
                if (r == 0 && tid < 512)
                    csf(A.lny1 + (size_t)b * 512 + tid, xsw[tid]);
                gemv_all<16, 512>(xsw, A.crossW + ((size_t)(l * 4)) * 262144,
                                  512, h * 64, part);
                if (tid < 64)
                    qch[tid] = gemv_allr<16>(part)
                             + A.crossB[(l * 4) * 512 + h * 64 + tid];
                __syncthreads();
                {   // qt[b,h,D-half] = 0.125 * qch . Wk[D][h*64..]
                    int D = half * 256 + (tid >> 2), q4 = tid & 3;
                    const float* wr = A.crossW + ((size_t)(l * 4 + 1)) * 262144
                                    + (size_t)D * 512 + h * 64 + q4 * 16;
                    const float* qp = qch + q4 * 16;
                    float a = 0.f;
                    #pragma unroll
                    for (int j = 0; j < 16; j += 4) {
                        f32x4 wv = *(const f32x4*)(wr + j);
                        a += qp[j]*wv[0] + qp[j+1]*wv[1] + qp[j+2]*wv[2] + qp[j+3]*wv[3];
                    }
                    a += __shfl_xor(a, 1);
                    a += __shfl_xor(a, 2);
                    if (q4 == 0)
                        csf(A.qt + ((size_t)b * 8 + h) * 512 + D, a * 0.125f);
                }
            }
            gbar(bar, b);

            // ------------ S5: flash cross-attn from LDS (role = chunk) -----
            {
                float* qts = sm;            // [8][520]
                float* lge = sm + 4160;     // [8][128]
                float* wms = sm + 5184;     // [16]
                float* wss = sm + 5200;     // [16]
                #pragma unroll
                for (int it = 0; it < 2; it++) {
                    int p = (tid + it * 1024) * 2;
                    float2 v = clf2(A.qt + (size_t)b * 4096 + p);
                    int row = p >> 9, d = p & 511;
                    qts[row * 520 + d] = v.x;
                    qts[row * 520 + d + 1] = v.y;
                }
                __syncthreads();
                #pragma unroll
                for (int it = 0; it < 4; it++) {
                    int key = it * 32 + (tid >> 5);
                    int hh = (tid >> 2) & 7, pq = tid & 3;
                    const ushort_t* er = encL + key * 520;
                    const float* q = qts + hh * 520;
                    float a0 = 0.f, a1 = 0.f;
                    #pragma unroll
                    for (int ch = 0; ch < 16; ch++) {
                        int c8 = (pq + ch * 4) * 8;
                        us8 ev8 = *(const us8*)(er + c8);
                        const float* qp = q + c8;
                        a0 += bf2f(ev8[0])*qp[0] + bf2f(ev8[1])*qp[1]
                            + bf2f(ev8[2])*qp[2] + bf2f(ev8[3])*qp[3];
                        a1 += bf2f(ev8[4])*qp[4] + bf2f(ev8[5])*qp[5]
                            + bf2f(ev8[6])*qp[6] + bf2f(ev8[7])*qp[7];
                    }
                    float acc = a0 + a1;
                    acc += __shfl_xor(acc, 1);
                    acc += __shfl_xor(acc, 2);
                    if (pq == 0)
                        lge[hh * 128 + key] = (padL[key] != 0.f) ? -2e30f : acc;
                }
                __syncthreads();
                {   // softmax over this chunk's 128 keys (wave = half a head)
                    int hh = tid >> 7, k = tid & 127;
                    float lv = lge[hh * 128 + k];
                    float mv = wave_max(lv);
                    if ((tid & 63) == 0) wms[tid >> 6] = mv;
                    __syncthreads();
                    float m = fmaxf(wms[hh * 2], wms[hh * 2 + 1]);
                    float ev = __expf(lv - m);
                    float sv = wave_sum(ev);
                    if ((tid & 63) == 0) wss[tid >> 6] = sv;
                    lge[hh * 128 + k] = ev;
                    __syncthreads();
                    if (tid < 8) {
                        int bc = b * 16 + r;
                        csf(A.Pm2 + bc * 8 + tid, fmaxf(wms[tid * 2], wms[tid * 2 + 1]));
                        csf(A.Ps2 + bc * 8 + tid, wss[tid * 2] + wss[tid * 2 + 1]);
                    }
                }
                __syncthreads();
                {   // z = sum_k ev * enc_k (LDS)
                    int hz = tid >> 7, ii = tid & 127;
                    f32x4 z = {0.f, 0.f, 0.f, 0.f};
                    const ushort_t* ep2 = encL + ii * 4;
                    const float* le = lge + hz * 128;
                    #pragma unroll 4
                    for (int k = 0; k < 128; k++) {
                        float ev = le[k];
                        us4 e4 = *(const us4*)(ep2 + k * 520);
                        z[0] += ev * bf2f(e4[0]); z[1] += ev * bf2f(e4[1]);
                        z[2] += ev * bf2f(e4[2]); z[3] += ev * bf2f(e4[3]);
                    }
                    float* dst = A.Pz + ((size_t)((b * 16 + r) * 8 + hz)) * 512 + ii * 4;
                    csf2(dst, z[0], z[1]);
                    csf2(dst + 2, z[2], z[3]);
                }
            }
            gbar(bar, b);

            // ------------ S6: combine chunks + Wv slice --------------------
            {
                int h = r >> 1, half = r & 1;
                float* zs = sm;            // 512
                float* zs2 = sm + 512;     // 2048 (4 quarters)
                float* ecs = sm + 2560;    // 17
                float* part = sm + 2624;   // 512
                if (tid < 16) {
                    float mcv = clf(A.Pm2 + (b * 16 + tid) * 8 + h);
                    float mm = mcv;
                    mm = fmaxf(mm, __shfl_xor(mm, 1));
                    mm = fmaxf(mm, __shfl_xor(mm, 2));
                    mm = fmaxf(mm, __shfl_xor(mm, 4));
                    mm = fmaxf(mm, __shfl_xor(mm, 8));
                    float ec = __expf(mcv - mm);
                    float sv = ec * clf(A.Ps2 + (b * 16 + tid) * 8 + h);
                    sv += __shfl_xor(sv, 1); sv += __shfl_xor(sv, 2);
                    sv += __shfl_xor(sv, 4); sv += __shfl_xor(sv, 8);
                    ecs[tid] = ec;
                    if (tid == 0) ecs[16] = 1.f / sv;
                }
                __syncthreads();
                {   // 4 quarters x 256 col-pairs, clf2 loads
                    int cp = (tid & 255) * 2, qtr = tid >> 8;
                    float a0 = 0.f, a1 = 0.f;
                    #pragma unroll
                    for (int j = 0; j < 4; j++) {
                        int cc = qtr * 4 + j;
                        float2 v = clf2(A.Pz + ((size_t)(b * 16 + cc) * 8 + h) * 512 + cp);
                        a0 += ecs[cc] * v.x; a1 += ecs[cc] * v.y;
                    }
                    zs2[qtr * 512 + cp] = a0;
                    zs2[qtr * 512 + cp + 1] = a1;
                }
                __syncthreads();
                if (tid < 512)
                    zs[tid] = (zs2[tid] + zs2[512 + tid] + zs2[1024 + tid]
                             + zs2[1536 + tid]) * ecs[16];
                __syncthreads();
                gemv_all<8, 512>(zs, A.crossW + ((size_t)(l * 4 + 2)) * 262144,
                                 512, h * 64 + half * 32, part);
                if (tid < 32) {
                    int col = h * 64 + half * 32 + tid;
                    csf(A.attnb + (size_t)b * 512 + col,
                        gemv_allr<8>(part) + A.crossB[(l * 4 + 2) * 512 + col]);
                }
            }
            gbar(bar, b);

            // ------------ S7: y2 slice = attnb@Wco + bco + lny1 ------------
            {
                float* xa = sm;            // 512
                float* part = sm + 512;    // 512
                if (tid < 256) {
                    float2 v = clf2(A.attnb + (size_t)b * 512 + tid * 2);
                    xa[tid * 2] = v.x; xa[tid * 2 + 1] = v.y;
                }
                __syncthreads();
                gemv_all<8, 512>(xa, A.crossW + ((size_t)(l * 4 + 3)) * 262144,
                                 512, r * 32, part);
                if (tid < 32) {
                    int col = r * 32 + tid;
                    csf(A.y2 + (size_t)b * 512 + col,
                        gemv_allr<8>(part) + A.crossB[(l * 4 + 3) * 512 + col]
                        + clf(A.lny1 + (size_t)b * 512 + col));
                }
            }
            gbar(bar, b);

            // ------------ S8: tmpb slice (128 cols) = relu(LN(y2)@W1) ------
            {
                float* xsw = sm;           // 512
                float* red = sm + 512;     // 32
                float* part = sm + 1024;   // 2048 (NCQ=32)
                ln512b(A.y2 + (size_t)b * 512, A.lng + (l * 3 + 1) * 512,
                       A.lnb + (l * 3 + 1) * 512, 1, xsw, red);
                if (r == 0 && tid < 512)
                    csf(A.lny2 + (size_t)b * 512 + tid, xsw[tid]);
                gemv_all<32, 512>(xsw, A.fW1 + (size_t)l * 512 * 2048,
                                  2048, r * 128, part);
                if (tid < 128) {
                    int col = r * 128 + tid;
                    csf(A.tmpb + (size_t)b * 2048 + col,
                        fmaxf(gemv_allr<32>(part) + A.fb1[l * 2048 + col], 0.f));
                }
            }
            gbar(bar, b);

            // ------------ S9: y3 slice = tmpb@W2 + b2 + lny2 ---------------
            {
                float* ts = sm;            // 2048
                float* part = sm + 2048;   // 512
                {
                    float2 v = clf2(A.tmpb + (size_t)b * 2048 + tid * 2);
                    ts[tid * 2] = v.x; ts[tid * 2 + 1] = v.y;
                }
                __syncthreads();
                gemv_all<8, 2048>(ts, A.fW2 + (size_t)l * 2048 * 512,
                                  512, r * 32, part);
                if (tid < 32) {
                    int col = r * 32 + tid;
                    csf(A.y3 + (size_t)b * 512 + col,
                        gemv_allr<8>(part) + A.fb2[l * 512 + col]
                        + clf(A.lny2 + (size_t)b * 512 + col));
                }
            }
            gbar(bar, b);
        } // l

        // ---------------- S_out: logits slice (16 cols/role) ---------------
        {
            float* xsw = sm;           // 512
            float* red = sm + 512;     // 32
            float* part = sm + 1024;   // 256 (NCQ=4)
            ln512b(A.y3 + (size_t)b * 512, A.lng + 11 * 512, A.lnb + 11 * 512,
                   1, xsw, red);
            gemv_all<4, 512>(xsw, A.outW, 256, r * 16, part);
            if (tid < 16) {
                int col = r * 16 + tid;
                csf(A.out + (size_t)b * 4096 + t * 256 + col,
                    gemv_allr<4>(part) + A.outB[col]);
            }
        }
        gbar(bar, b);
    } // t
}

// ---------------------------------------------------------------------------

extern "C" void kernel_launch(void* const* d_in, const int* in_sizes, int n_in,
                              void* d_out, int out_size, void* d_ws, size_t ws_size,
                              hipStream_t stream) {
    Args A;
    A.enc    = (const float*)d_in[0];
    A.encIn  = (const float*)d_in[1];
    A.embW   = (const float*)d_in[2];
    A.embB   = (const float*)d_in[3];
    A.outW   = (const float*)d_in[4];
    A.outB   = (const float*)d_in[5];
    A.selfW  = (const float*)d_in[6];
    A.selfB  = (const float*)d_in[7];
    A.crossW = (const float*)d_in[8];
    A.crossB = (const float*)d_in[9];
    A.fW1    = (const float*)d_in[10];
    A.fb1    = (const float*)d_in[11];
    A.fW2    = (const float*)d_in[12];
    A.fb2    = (const float*)d_in[13];
    A.lng    = (const float*)d_in[14];
    A.lnb    = (const float*)d_in[15];
    A.out    = (float*)d_out;

    char* ws = (char*)d_ws;
    size_t off = 0;
    auto alloc = [&](size_t bytes) -> char* {
        char* p = ws + off;
        off = (off + bytes + 255) & ~(size_t)255;
        return p;
    };
    char* barrier = alloc(4096);
    A.bar = (unsigned*)barrier;
    A.x0    = (float*)alloc(16 * 512 * 4);
    A.qbuf  = (float*)alloc(16 * 512 * 4);
    A.y1    = (float*)alloc(16 * 512 * 4);
    A.y2    = (float*)alloc(16 * 512 * 4);
    A.y3    = (float*)alloc(16 * 512 * 4);
    A.attnb = (float*)alloc(16 * 512 * 4);
    A.lny1  = (float*)alloc(16 * 512 * 4);
    A.lny2  = (float*)alloc(16 * 512 * 4);
    A.qt    = (float*)alloc((size_t)16 * 8 * 512 * 4);
    A.Pm2   = (float*)alloc(16 * 16 * 8 * 4);
    A.Ps2   = (float*)alloc(16 * 16 * 8 * 4);
    A.Pz    = (float*)alloc((size_t)16 * 16 * 8 * 512 * 4);
    A.tmpb  = (float*)alloc((size_t)16 * 2048 * 4);
    A.selfK = (float*)alloc((size_t)4 * 16 * 16 * 512 * 4);
    A.selfV = (float*)alloc((size_t)4 * 16 * 16 * 512 * 4);
    if (off > ws_size) return;   // ~9 MB — always fits

    hipMemsetAsync(barrier, 0, 4096, stream);
    k_mega<<<dim3(NB), dim3(NTHR), 0, stream>>>(A);
}

// Round 14
// 4860.311 us; speedup vs baseline: 2.8558x; 1.0280x over previous
//
#include <hip/hip_runtime.h>

// ---------------------------------------------------------------------------
// Decoder_49005576847865 — persistent decoder, independent batch groups.
//   B=16, d=512, H=8 (dh=64), L=4, dff=2048, Lenc=2048, 16 steps, vocab=256.
// Round 14: round-13 (bf16 weights) + BARRIER ADDRESS FIX. Round 13's
//   gbar_all state (bar[768]/bar[800]) collided with group 8/9 release lines
//   => batch-8 barriers fell through (racy replays). Global barrier state now
//   at bar[1024]/bar[1056]; barrier region 8KB. Nothing else changed.
// ---------------------------------------------------------------------------

typedef unsigned short ushort_t;
typedef __attribute__((ext_vector_type(4))) float f32x4;
typedef __attribute__((ext_vector_type(8))) unsigned short us8;
typedef __attribute__((ext_vector_type(4))) unsigned short us4;

#define NB 256
#define NTHR 1024

__device__ __forceinline__ float bf2f(ushort_t u) {
    union { unsigned int i; float f; } v; v.i = ((unsigned int)u) << 16; return v.f;
}
__device__ __forceinline__ ushort_t f2bf(float f) {
    union { unsigned int i; float f; } v; v.f = f;
    return (ushort_t)((v.i + 0x7FFF + ((v.i >> 16) & 1)) >> 16);   // RNE
}
__device__ __forceinline__ f32x4 b2f4(us4 w) {
    return (f32x4){bf2f(w[0]), bf2f(w[1]), bf2f(w[2]), bf2f(w[3])};
}
__device__ __forceinline__ float wave_sum(float v) {
    #pragma unroll
    for (int m = 32; m; m >>= 1) v += __shfl_xor(v, m);
    return v;
}
__device__ __forceinline__ float wave_max(float v) {
    #pragma unroll
    for (int m = 32; m; m >>= 1) v = fmaxf(v, __shfl_xor(v, m));
    return v;
}

// ---- coherent (agent-scope, fence-free) access for mutable activations -----
union U64C { unsigned long long u; float2 f; us4 s4; };
__device__ __forceinline__ float clf(const float* p) {
    return __hip_atomic_load(p, __ATOMIC_RELAXED, __HIP_MEMORY_SCOPE_AGENT);
}
__device__ __forceinline__ void csf(float* p, float v) {
    __hip_atomic_store(p, v, __ATOMIC_RELAXED, __HIP_MEMORY_SCOPE_AGENT);
}
__device__ __forceinline__ float2 clf2(const float* p) {
    U64C c; c.u = __hip_atomic_load((unsigned long long*)p, __ATOMIC_RELAXED,
                                    __HIP_MEMORY_SCOPE_AGENT);
    return c.f;
}
__device__ __forceinline__ void csf2(float* p, float x, float y) {
    U64C c; c.f.x = x; c.f.y = y;
    __hip_atomic_store((unsigned long long*)p, c.u, __ATOMIC_RELAXED,
                       __HIP_MEMORY_SCOPE_AGENT);
}
__device__ __forceinline__ void csu4(ushort_t* p, us4 v) {
    U64C c; c.s4 = v;
    __hip_atomic_store((unsigned long long*)p, c.u, __ATOMIC_RELAXED,
                       __HIP_MEMORY_SCOPE_AGENT);
}

// ---- fence-free PER-GROUP barrier (16 blocks, relaxed-only) -----------------
// state layout in bar (uint index): group g cnt at g*32, rel at 512+g*32
// (0..992). GLOBAL barrier: cnt at 1024, rel at 1056. Region = 8KB.
__device__ __forceinline__ void gbar(unsigned* bar, int g) {
    __syncthreads();
    if (threadIdx.x == 0) {
        unsigned* cnt = bar + g * 32;
        unsigned* rel = bar + 512 + g * 32;
        unsigned a = __hip_atomic_fetch_add(cnt, 1u, __ATOMIC_RELAXED,
                                            __HIP_MEMORY_SCOPE_AGENT);
        unsigned e = (a >> 4) + 1u;
        if ((a & 15u) == 15u) {
            __hip_atomic_store(rel, e, __ATOMIC_RELAXED, __HIP_MEMORY_SCOPE_AGENT);
        } else {
            while ((int)(__hip_atomic_load(rel, __ATOMIC_RELAXED,
                                           __HIP_MEMORY_SCOPE_AGENT) - e) < 0)
                __builtin_amdgcn_s_sleep(1);
        }
    }
    __syncthreads();
}

// ---- one-time GLOBAL barrier (256 blocks) — state DISJOINT from gbar's -----
__device__ __forceinline__ void gbar_all(unsigned* bar) {
    __syncthreads();
    if (threadIdx.x == 0) {
        unsigned* cnt = bar + 1024;
        unsigned* rel = bar + 1056;
        unsigned a = __hip_atomic_fetch_add(cnt, 1u, __ATOMIC_RELAXED,
                                            __HIP_MEMORY_SCOPE_AGENT);
        unsigned e = (a >> 8) + 1u;
        if ((a & 255u) == 255u) {
            __hip_atomic_store(rel, e, __ATOMIC_RELAXED, __HIP_MEMORY_SCOPE_AGENT);
        } else {
            while ((int)(__hip_atomic_load(rel, __ATOMIC_RELAXED,
                                           __HIP_MEMORY_SCOPE_AGENT) - e) < 0)
                __builtin_amdgcn_s_sleep(1);
        }
    }
    __syncthreads();
}

// ---- block-wide LN, single pass (sum+sumsq); red needs 32 floats -----------
__device__ __forceinline__ void ln512b(const float* __restrict__ row,
                                       const float* __restrict__ g,
                                       const float* __restrict__ be,
                                       int use_ln, float* dst, float* red) {
    int tid = threadIdx.x;
    float a = (tid < 512) ? clf(row + tid) : 0.f;
    if (use_ln) {
        float s = a, s2 = a * a;
        #pragma unroll
        for (int m = 32; m; m >>= 1) {
            s  += __shfl_xor(s, m);
            s2 += __shfl_xor(s2, m);
        }
        if ((tid & 63) == 0) { red[tid >> 6] = s; red[16 + (tid >> 6)] = s2; }
        __syncthreads();
        float ts = 0.f, ts2 = 0.f;
        #pragma unroll
        for (int i = 0; i < 8; i++) { ts += red[i]; ts2 += red[16 + i]; }
        float mu = ts * (1.f / 512.f);
        float var = ts2 * (1.f / 512.f) - mu * mu;
        float rstd = rsqrtf(var + 1e-6f);
        if (tid < 512) dst[tid] = (a - mu) * rstd * g[tid] + be[tid];
    } else {
        if (tid < 512) dst[tid] = a;
    }
    __syncthreads();
}

// ---- all-thread split-K GEMV, fp32 weights (emb/out only) ------------------
template<int NCQ, int K>
__device__ __forceinline__ void gemv_allf(const float* xs, const float* __restrict__ W,
                                          int ldw, int col0, float* part) {
    constexpr int S = 1024 / NCQ;
    constexpr int KS = K / S;
    int tid = threadIdx.x;
    int cq = tid & (NCQ - 1), ks = tid / NCQ;
    const float* Wp = W + (size_t)(ks * KS) * ldw + col0 + cq * 4;
    const float* xp = xs + ks * KS;
    f32x4 acc = {0.f, 0.f, 0.f, 0.f};
    #pragma unroll
    for (int r = 0; r < KS; r++)
        acc += xp[r] * *(const f32x4*)(Wp + (size_t)r * ldw);
    #pragma unroll
    for (int m = NCQ; m < 64; m <<= 1) {
        acc[0] += __shfl_xor(acc[0], m);
        acc[1] += __shfl_xor(acc[1], m);
        acc[2] += __shfl_xor(acc[2], m);
        acc[3] += __shfl_xor(acc[3], m);
    }
    int wave = tid >> 6, lane = tid & 63;
    if (lane < NCQ) *(f32x4*)(part + (wave * NCQ + lane) * 4) = acc;
    __syncthreads();
}

// ---- all-thread split-K GEMV, bf16 weights (us4 loads) ---------------------
template<int NCQ, int K>
__device__ __forceinline__ void gemv_allb(const float* xs, const ushort_t* __restrict__ W,
                                          int ldw, int col0, float* part) {
    constexpr int S = 1024 / NCQ;
    constexpr int KS = K / S;
    int tid = threadIdx.x;
    int cq = tid & (NCQ - 1), ks = tid / NCQ;
    const ushort_t* Wp = W + (size_t)(ks * KS) * ldw + col0 + cq * 4;
    const float* xp = xs + ks * KS;
    f32x4 acc = {0.f, 0.f, 0.f, 0.f};
    #pragma unroll
    for (int r = 0; r < KS; r++)
        acc += xp[r] * b2f4(*(const us4*)(Wp + (size_t)r * ldw));
    #pragma unroll
    for (int m = NCQ; m < 64; m <<= 1) {
        acc[0] += __shfl_xor(acc[0], m);
        acc[1] += __shfl_xor(acc[1], m);
        acc[2] += __shfl_xor(acc[2], m);
        acc[3] += __shfl_xor(acc[3], m);
    }
    int wave = tid >> 6, lane = tid & 63;
    if (lane < NCQ) *(f32x4*)(part + (wave * NCQ + lane) * 4) = acc;
    __syncthreads();
}
template<int NCQ>
__device__ __forceinline__ float gemv_allr(const float* part) {
    float a = 0.f;
    #pragma unroll
    for (int w = 0; w < 16; w++) a += part[w * NCQ * 4 + threadIdx.x];
    return a;
}

struct Args {
    const float *enc, *encIn, *embW, *embB, *outW, *outB;
    const float *selfW, *selfB, *crossW, *crossB;
    const float *fW1, *fb1, *fW2, *fb2, *lng, *lnb;
    float* out;
    unsigned* bar;
    float *x0, *qbuf, *y1, *y2, *y3, *attnb;
    float *lny1, *lny2, *qt, *Pm2, *Ps2, *Pz, *tmpb, *selfK, *selfV;
    ushort_t *selfWb, *crossWb, *fW1b, *fW2b;
};

// ---------------------------------------------------------------------------

__global__ __launch_bounds__(NTHR, 4) void k_mega(Args A) {
    __shared__ ushort_t encL[128 * 520];   // 520-padded rows (133120 B)
    __shared__ float padL[128];
    __shared__ float sm[6400];             // 25.6 KB stage scratch
    const int bid = blockIdx.x, tid = threadIdx.x;
    const int b = bid >> 4, r = bid & 15;
    unsigned* bar = A.bar;

    // ---------------- P0: enc->LDS, pad flags, weights->bf16 ---------------
    {
        const float* ep = A.enc + ((size_t)b * 2048 + r * 128) * 512;
        #pragma unroll 4
        for (int it = 0; it < 16; it++) {
            int idx = tid + it * 1024;            // us4-chunk id < 16384
            int key = idx >> 7;
            int d = (idx & 127) * 4;
            float4 v = *(const float4*)(ep + (size_t)key * 512 + d);
            us4 o; o[0] = f2bf(v.x); o[1] = f2bf(v.y); o[2] = f2bf(v.z); o[3] = f2bf(v.w);
            *(us4*)(encL + key * 520 + d) = o;
        }
        int key = tid >> 3, sub = tid & 7;
        const float* p = A.encIn + ((size_t)b * 2048 + r * 128 + key) * 128 + sub * 16;
        int ok = 1;
        #pragma unroll
        for (int j = 0; j < 4; j++) {
            float4 v = *(const float4*)(p + j * 4);
            ok &= (v.x == 0.f) & (v.y == 0.f) & (v.z == 0.f) & (v.w == 0.f);
        }
        ok &= __shfl_xor(ok, 1); ok &= __shfl_xor(ok, 2); ok &= __shfl_xor(ok, 4);
        if (sub == 0) padL[key] = ok ? 1.f : 0.f;
        // weight conversion: 4 arrays x 4,194,304 elems; 16384 per block each
        const float* srcs[4] = {A.selfW, A.crossW, A.fW1, A.fW2};
        ushort_t* dsts[4] = {A.selfWb, A.crossWb, A.fW1b, A.fW2b};
        #pragma unroll
        for (int a = 0; a < 4; a++) {
            const float* s = srcs[a];
            ushort_t* d = dsts[a];
            #pragma unroll
            for (int it = 0; it < 4; it++) {
                size_t i = (size_t)bid * 16384 + (size_t)(it * 1024 + tid) * 4;
                float4 v = *(const float4*)(s + i);
                us4 o; o[0] = f2bf(v.x); o[1] = f2bf(v.y); o[2] = f2bf(v.z); o[3] = f2bf(v.w);
                csu4(d + i, o);
            }
        }
    }
    gbar_all(bar);   // weights visible to all groups before first use

    for (int t = 0; t < 16; t++) {
        // ---------------- S_emb: x0 slice (32 cols/role) -------------------
        {
            float* tok = sm;            // 256
            float* part = sm + 256;     // 512
            if (tid < 256)
                tok[tid] = (t == 0) ? 1.f
                         : clf(A.out + (size_t)b * 4096 + (t - 1) * 256 + tid);
            __syncthreads();
            gemv_allf<8, 256>(tok, A.embW, 512, r * 32, part);
            if (tid < 32) {
                float acc = gemv_allr<8>(part);
                int col = r * 32 + tid;
                float expo = (2.0f * (float)(col >> 1)) * (1.f / 512.f);
                float ang = (float)t * powf(10000.0f, -expo);
                float pv = (col & 1) ? cosf(ang) : sinf(ang);
                csf(A.x0 + (size_t)b * 512 + col,
                    (acc + A.embB[col]) * 22.627416997969522f + pv);
            }
        }
        gbar(bar, b);

        for (int l = 0; l < 4; l++) {
            const float* src = (l == 0) ? A.x0 : A.y3;
            const float* gP = (l == 0) ? nullptr : A.lng + ((l - 1) * 3 + 2) * 512;
            const float* bP = (l == 0) ? nullptr : A.lnb + ((l - 1) * 3 + 2) * 512;
            int ulnP = (l != 0);

            // ------------ S1: q/k/v fused triple GEMV (32 cols each) -------
            {
                float* xs = sm;            // 512
                float* red = sm + 512;     // 32
                float* part = sm + 1024;   // 3*512
                ln512b(src + (size_t)b * 512, gP, bP, ulnP, xs, red);
                int cq = tid & 7, ks = tid >> 3;         // 128 slices of 4
                const float* xp = xs + ks * 4;
                f32x4 a0 = {0.f,0.f,0.f,0.f}, a1 = a0, a2 = a0;
                const ushort_t* W0 = A.selfWb + ((size_t)(l * 4 + 0)) * 262144
                                   + (size_t)(ks * 4) * 512 + r * 32 + cq * 4;
                const ushort_t* W1 = W0 + 262144;
                const ushort_t* W2 = W1 + 262144;
                #pragma unroll
                for (int rr = 0; rr < 4; rr++) {
                    float x = xp[rr];
                    a0 += x * b2f4(*(const us4*)(W0 + (size_t)rr * 512));
                    a1 += x * b2f4(*(const us4*)(W1 + (size_t)rr * 512));
                    a2 += x * b2f4(*(const us4*)(W2 + (size_t)rr * 512));
                }
                #pragma unroll
                for (int m = 8; m < 64; m <<= 1) {
                    #pragma unroll
                    for (int j = 0; j < 4; j++) {
                        a0[j] += __shfl_xor(a0[j], m);
                        a1[j] += __shfl_xor(a1[j], m);
                        a2[j] += __shfl_xor(a2[j], m);
                    }
                }
                int wave = tid >> 6, lane = tid & 63;
                if (lane < 8) {
                    *(f32x4*)(part + (wave * 8 + lane) * 4) = a0;
                    *(f32x4*)(part + 512 + (wave * 8 + lane) * 4) = a1;
                    *(f32x4*)(part + 1024 + (wave * 8 + lane) * 4) = a2;
                }
                __syncthreads();
                if (tid < 96) {
                    int m = tid >> 5, j = tid & 31;
                    float a = 0.f;
                    #pragma unroll
                    for (int w = 0; w < 16; w++) a += part[m * 512 + w * 32 + j];
                    int col = r * 32 + j;
                    a += A.selfB[(l * 4 + m) * 512 + col];
                    if (m == 0) csf(A.qbuf + (size_t)b * 512 + col, a);
                    else if (m == 1)
                        csf(A.selfK + (((size_t)l * 16 + b) * 16 + t) * 512 + col, a);
                    else
                        csf(A.selfV + (((size_t)l * 16 + b) * 16 + t) * 512 + col, a);
                }
            }
            gbar(bar, b);

            // ------------ S2: self-attn + Wo slice + residual --------------
            {
                float* xr = sm;            // 512
                float* qs = sm + 512;      // 512 (later reused for AV result)
                float* as2 = sm + 1024;    // 1024
                float* lg = sm + 2048;     // 128
                float* red = sm + 2176;    // 32
                float* part = sm + 2560;   // 512
                ln512b(src + (size_t)b * 512, gP, bP, ulnP, xr, red);
                if (tid < 256) {
                    float2 v = clf2(A.qbuf + (size_t)b * 512 + tid * 2);
                    qs[tid * 2] = v.x; qs[tid * 2 + 1] = v.y;
                }
                __syncthreads();
                const float* Kb = A.selfK + ((size_t)l * 16 + b) * 16 * 512;
                const float* Vb = A.selfV + ((size_t)l * 16 + b) * 16 * 512;
                if (tid < 512) {
                    int idx = tid >> 2, q4 = tid & 3;
                    int h = idx >> 4, j = idx & 15;
                    if (j <= t) {
                        const float* kp = Kb + (size_t)j * 512 + h * 64 + q4 * 16;
                        const float* qp = qs + h * 64 + q4 * 16;
                        float s = 0.f;
                        #pragma unroll
                        for (int d = 0; d < 16; d += 2) {
                            float2 kv = clf2(kp + d);
                            s += qp[d] * kv.x + qp[d + 1] * kv.y;
                        }
                        s += __shfl_xor(s, 1);
                        s += __shfl_xor(s, 2);
                        if (q4 == 0) lg[h * 16 + j] = s * 0.125f;
                    }
                }
                __syncthreads();
                if (tid < 8) {
                    float m = -1e30f;
                    for (int j = 0; j <= t; j++) m = fmaxf(m, lg[tid * 16 + j]);
                    float ssum = 0.f;
                    for (int j = 0; j <= t; j++) {
                        float e = __expf(lg[tid * 16 + j] - m);
                        lg[tid * 16 + j] = e; ssum += e;
                    }
                    float inv = 1.f / ssum;
                    for (int j = 0; j <= t; j++) lg[tid * 16 + j] *= inv;
                }
                __syncthreads();
                {   // AV on all 1024 threads (j parity split)
                    int col = tid & 511, jh = tid >> 9;
                    float a = 0.f;
                    for (int j = jh; j <= t; j += 2)
                        a += lg[(col >> 6) * 16 + j] * clf(Vb + (size_t)j * 512 + col);
                    as2[jh * 512 + col] = a;
                }
                __syncthreads();
                if (tid < 512) qs[tid] = as2[tid] + as2[512 + tid];
                __syncthreads();
                gemv_allb<8, 512>(qs, A.selfWb + ((size_t)(l * 4 + 3)) * 262144,
                                  512, r * 32, part);
                if (tid < 32) {
                    int col = r * 32 + tid;
                    csf(A.y1 + (size_t)b * 512 + col,
                        gemv_allr<8>(part) + A.selfB[(l * 4 + 3) * 512 + col] + xr[col]);
                }
            }
            gbar(bar, b);

            // ------------ S34: qc_h (redundant per half) + qt_h half -------
            {
                int h = r >> 1, half = r & 1;
                float* xsw = sm;           // 512
                float* red = sm + 512;     // 32
                float* qch = sm + 544;     // 64
                float* part = sm + 1024;   // 1024 (NCQ=16)
                ln512b(A.y1 + (size_t)b * 512, A.lng + (l * 3) * 512,
                       A.lnb + (l * 3) * 512, 1, xsw, red);
                if (r == 0 && tid < 512)
                    csf(A.lny1 + (size_t)b * 512 + tid, xsw[tid]);
                gemv_allb<16, 512>(xsw, A.crossWb + ((size_t)(l * 4)) * 262144,
                                   512, h * 64, part);
                if (tid < 64)
                    qch[tid] = gemv_allr<16>(part)
                             + A.crossB[(l * 4) * 512 + h * 64 + tid];
                __syncthreads();
                {   // qt[b,h,D-half] = 0.125 * qch . Wk[D][h*64..]
                    int D = half * 256 + (tid >> 2), q4 = tid & 3;
                    const ushort_t* wr = A.crossWb + ((size_t)(l * 4 + 1)) * 262144
                                       + (size_t)D * 512 + h * 64 + q4 * 16;
                    const float* qp = qch + q4 * 16;
                    float a = 0.f;
                    #pragma unroll
                    for (int j = 0; j < 16; j += 4) {
                        f32x4 wv = b2f4(*(const us4*)(wr + j));
                        a += qp[j]*wv[0] + qp[j+1]*wv[1] + qp[j+2]*wv[2] + qp[j+3]*wv[3];
                    }
                    a += __shfl_xor(a, 1);
                    a += __shfl_xor(a, 2);
                    if (q4 == 0)
                        csf(A.qt + ((size_t)b * 8 + h) * 512 + D, a * 0.125f);
                }
            }
            gbar(bar, b);

            // ------------ S5: flash cross-attn from LDS (role = chunk) -----
            {
                float* qts = sm;            // [8][520]
                float* lge = sm + 4160;     // [8][128]
                float* wms = sm + 5184;     // [16]
                float* wss = sm + 5200;     // [16]
                #pragma unroll
                for (int it = 0; it < 2; it++) {
                    int p = (tid + it * 1024) * 2;
                    float2 v = clf2(A.qt + (size_t)b * 4096 + p);
                    int row = p >> 9, d = p & 511;
                    qts[row * 520 + d] = v.x;
                    qts[row * 520 + d + 1] = v.y;
                }
                __syncthreads();
                #pragma unroll
                for (int it = 0; it < 4; it++) {
                    int key = it * 32 + (tid >> 5);
                    int hh = (tid >> 2) & 7, pq = tid & 3;
                    const ushort_t* er = encL + key * 520;
                    const float* q = qts + hh * 520;
                    float a0 = 0.f, a1 = 0.f;
                    #pragma unroll
                    for (int ch = 0; ch < 16; ch++) {
                        int c8 = (pq + ch * 4) * 8;
                        us8 ev8 = *(const us8*)(er + c8);
                        const float* qp = q + c8;
                        a0 += bf2f(ev8[0])*qp[0] + bf2f(ev8[1])*qp[1]
                            + bf2f(ev8[2])*qp[2] + bf2f(ev8[3])*qp[3];
                        a1 += bf2f(ev8[4])*qp[4] + bf2f(ev8[5])*qp[5]
                            + bf2f(ev8[6])*qp[6] + bf2f(ev8[7])*qp[7];
                    }
                    float acc = a0 + a1;
                    acc += __shfl_xor(acc, 1);
                    acc += __shfl_xor(acc, 2);
                    if (pq == 0)
                        lge[hh * 128 + key] = (padL[key] != 0.f) ? -2e30f : acc;
                }
                __syncthreads();
                {   // softmax over this chunk's 128 keys (wave = half a head)
                    int hh = tid >> 7, k = tid & 127;
                    float lv = lge[hh * 128 + k];
                    float mv = wave_max(lv);
                    if ((tid & 63) == 0) wms[tid >> 6] = mv;
                    __syncthreads();
                    float m = fmaxf(wms[hh * 2], wms[hh * 2 + 1]);
                    float ev = __expf(lv - m);
                    float sv = wave_sum(ev);
                    if ((tid & 63) == 0) wss[tid >> 6] = sv;
                    lge[hh * 128 + k] = ev;
                    __syncthreads();
                    if (tid < 8) {
                        int bc = b * 16 + r;
                        csf(A.Pm2 + bc * 8 + tid, fmaxf(wms[tid * 2], wms[tid * 2 + 1]));
                        csf(A.Ps2 + bc * 8 + tid, wss[tid * 2] + wss[tid * 2 + 1]);
                    }
                }
                __syncthreads();
                {   // z = sum_k ev * enc_k (LDS)
                    int hz = tid >> 7, ii = tid & 127;
                    f32x4 z = {0.f, 0.f, 0.f, 0.f};
                    const ushort_t* ep2 = encL + ii * 4;
                    const float* le = lge + hz * 128;
                    #pragma unroll 4
                    for (int k = 0; k < 128; k++) {
                        float ev = le[k];
                        us4 e4 = *(const us4*)(ep2 + k * 520);
                        z[0] += ev * bf2f(e4[0]); z[1] += ev * bf2f(e4[1]);
                        z[2] += ev * bf2f(e4[2]); z[3] += ev * bf2f(e4[3]);
                    }
                    float* dst = A.Pz + ((size_t)((b * 16 + r) * 8 + hz)) * 512 + ii * 4;
                    csf2(dst, z[0], z[1]);
                    csf2(dst + 2, z[2], z[3]);
                }
            }
            gbar(bar, b);

            // ------------ S6: combine chunks + Wv slice --------------------
            {
                int h = r >> 1, half = r & 1;
                float* zs = sm;            // 512
                float* zs2 = sm + 512;     // 2048 (4 quarters)
                float* ecs = sm + 2560;    // 17
                float* part = sm + 2624;   // 512
                if (tid < 16) {
                    float mcv = clf(A.Pm2 + (b * 16 + tid) * 8 + h);
                    float mm = mcv;
                    mm = fmaxf(mm, __shfl_xor(mm, 1));
                    mm = fmaxf(mm, __shfl_xor(mm, 2));
                    mm = fmaxf(mm, __shfl_xor(mm, 4));
                    mm = fmaxf(mm, __shfl_xor(mm, 8));
                    float ec = __expf(mcv - mm);
                    float sv = ec * clf(A.Ps2 + (b * 16 + tid) * 8 + h);
                    sv += __shfl_xor(sv, 1); sv += __shfl_xor(sv, 2);
                    sv += __shfl_xor(sv, 4); sv += __shfl_xor(sv, 8);
                    ecs[tid] = ec;
                    if (tid == 0) ecs[16] = 1.f / sv;
                }
                __syncthreads();
                {   // 4 quarters x 256 col-pairs, clf2 loads
                    int cp = (tid & 255) * 2, qtr = tid >> 8;
                    float a0 = 0.f, a1 = 0.f;
                    #pragma unroll
                    for (int j = 0; j < 4; j++) {
                        int cc = qtr * 4 + j;
                        float2 v = clf2(A.Pz + ((size_t)(b * 16 + cc) * 8 + h) * 512 + cp);
                        a0 += ecs[cc] * v.x; a1 += ecs[cc] * v.y;
                    }
                    zs2[qtr * 512 + cp] = a0;
                    zs2[qtr * 512 + cp + 1] = a1;
                }
                __syncthreads();
                if (tid < 512)
                    zs[tid] = (zs2[tid] + zs2[512 + tid] + zs2[1024 + tid]
                             + zs2[1536 + tid]) * ecs[16];
                __syncthreads();
                gemv_allb<8, 512>(zs, A.crossWb + ((size_t)(l * 4 + 2)) * 262144,
                                  512, h * 64 + half * 32, part);
                if (tid < 32) {
                    int col = h * 64 + half * 32 + tid;
                    csf(A.attnb + (size_t)b * 512 + col,
                        gemv_allr<8>(part) + A.crossB[(l * 4 + 2) * 512 + col]);
                }
            }
            gbar(bar, b);

            // ------------ S7: y2 slice = attnb@Wco + bco + lny1 ------------
            {
                float* xa = sm;            // 512
                float* part = sm + 512;    // 512
                if (tid < 256) {
                    float2 v = clf2(A.attnb + (size_t)b * 512 + tid * 2);
                    xa[tid * 2] = v.x; xa[tid * 2 + 1] = v.y;
                }
                __syncthreads();
                gemv_allb<8, 512>(xa, A.crossWb + ((size_t)(l * 4 + 3)) * 262144,
                                  512, r * 32, part);
                if (tid < 32) {
                    int col = r * 32 + tid;
                    csf(A.y2 + (size_t)b * 512 + col,
                        gemv_allr<8>(part) + A.crossB[(l * 4 + 3) * 512 + col]
                        + clf(A.lny1 + (size_t)b * 512 + col));
                }
            }
            gbar(bar, b);

            // ------------ S8: tmpb slice (128 cols) = relu(LN(y2)@W1) ------
            {
                float* xsw = sm;           // 512
                float* red = sm + 512;     // 32
                float* part = sm + 1024;   // 2048 (NCQ=32)
                ln512b(A.y2 + (size_t)b * 512, A.lng + (l * 3 + 1) * 512,
                       A.lnb + (l * 3 + 1) * 512, 1, xsw, red);
                if (r == 0 && tid < 512)
                    csf(A.lny2 + (size_t)b * 512 + tid, xsw[tid]);
                gemv_allb<32, 512>(xsw, A.fW1b + (size_t)l * 512 * 2048,
                                   2048, r * 128, part);
                if (tid < 128) {
                    int col = r * 128 + tid;
                    csf(A.tmpb + (size_t)b * 2048 + col,
                        fmaxf(gemv_allr<32>(part) + A.fb1[l * 2048 + col], 0.f));
                }
            }
            gbar(bar, b);

            // ------------ S9: y3 slice = tmpb@W2 + b2 + lny2 ---------------
            {
                float* ts = sm;            // 2048
                float* part = sm + 2048;   // 512
                {
                    float2 v = clf2(A.tmpb + (size_t)b * 2048 + tid * 2);
                    ts[tid * 2] = v.x; ts[tid * 2 + 1] = v.y;
                }
                __syncthreads();
                gemv_allb<8, 2048>(ts, A.fW2b + (size_t)l * 2048 * 512,
                                   512, r * 32, part);
                if (tid < 32) {
                    int col = r * 32 + tid;
                    csf(A.y3 + (size_t)b * 512 + col,
                        gemv_allr<8>(part) + A.fb2[l * 512 + col]
                        + clf(A.lny2 + (size_t)b * 512 + col));
                }
            }
            gbar(bar, b);
        } // l

        // ---------------- S_out: logits slice (16 cols/role) ---------------
        {
            float* xsw = sm;           // 512
            float* red = sm + 512;     // 32
            float* part = sm + 1024;   // 256 (NCQ=4)
            ln512b(A.y3 + (size_t)b * 512, A.lng + 11 * 512, A.lnb + 11 * 512,
                   1, xsw, red);
            gemv_allf<4, 512>(xsw, A.outW, 256, r * 16, part);
            if (tid < 16) {
                int col = r * 16 + tid;
                csf(A.out + (size_t)b * 4096 + t * 256 + col,
                    gemv_allr<4>(part) + A.outB[col]);
            }
        }
        gbar(bar, b);
    } // t
}

// ---------------------------------------------------------------------------

extern "C" void kernel_launch(void* const* d_in, const int* in_sizes, int n_in,
                              void* d_out, int out_size, void* d_ws, size_t ws_size,
                              hipStream_t stream) {
    Args A;
    A.enc    = (const float*)d_in[0];
    A.encIn  = (const float*)d_in[1];
    A.embW   = (const float*)d_in[2];
    A.embB   = (const float*)d_in[3];
    A.outW   = (const float*)d_in[4];
    A.outB   = (const float*)d_in[5];
    A.selfW  = (const float*)d_in[6];
    A.selfB  = (const float*)d_in[7];
    A.crossW = (const float*)d_in[8];
    A.crossB = (const float*)d_in[9];
    A.fW1    = (const float*)d_in[10];
    A.fb1    = (const float*)d_in[11];
    A.fW2    = (const float*)d_in[12];
    A.fb2    = (const float*)d_in[13];
    A.lng    = (const float*)d_in[14];
    A.lnb    = (const float*)d_in[15];
    A.out    = (float*)d_out;

    char* ws = (char*)d_ws;
    size_t off = 0;
    auto alloc = [&](size_t bytes) -> char* {
        char* p = ws + off;
        off = (off + bytes + 255) & ~(size_t)255;
        return p;
    };
    char* barrier = alloc(8192);   // group state 0..992, global state 1024/1056
    A.bar = (unsigned*)barrier;
    A.x0    = (float*)alloc(16 * 512 * 4);
    A.qbuf  = (float*)alloc(16 * 512 * 4);
    A.y1    = (float*)alloc(16 * 512 * 4);
    A.y2    = (float*)alloc(16 * 512 * 4);
    A.y3    = (float*)alloc(16 * 512 * 4);
    A.attnb = (float*)alloc(16 * 512 * 4);
    A.lny1  = (float*)alloc(16 * 512 * 4);
    A.lny2  = (float*)alloc(16 * 512 * 4);
    A.qt    = (float*)alloc((size_t)16 * 8 * 512 * 4);
    A.Pm2   = (float*)alloc(16 * 16 * 8 * 4);
    A.Ps2   = (float*)alloc(16 * 16 * 8 * 4);
    A.Pz    = (float*)alloc((size_t)16 * 16 * 8 * 512 * 4);
    A.tmpb  = (float*)alloc((size_t)16 * 2048 * 4);
    A.selfK = (float*)alloc((size_t)4 * 16 * 16 * 512 * 4);
    A.selfV = (float*)alloc((size_t)4 * 16 * 16 * 512 * 4);
    A.selfWb  = (ushort_t*)alloc((size_t)4 * 4 * 512 * 512 * 2);
    A.crossWb = (ushort_t*)alloc((size_t)4 * 4 * 512 * 512 * 2);
    A.fW1b    = (ushort_t*)alloc((size_t)4 * 512 * 2048 * 2);
    A.fW2b    = (ushort_t*)alloc((size_t)4 * 2048 * 512 * 2);
    if (off > ws_size) return;   // ~40.7 MB; ws proven >= 42.7 MB (round 2)

    hipMemsetAsync(barrier, 0, 8192, stream);
    k_mega<<<dim3(NB), dim3(NTHR), 0, stream>>>(A);
}